// Round 11
// baseline (673.034 us; speedup 1.0000x reference)
//
#include <hip/hip_runtime.h>
#include <hip/hip_bf16.h>
#include <math.h>

#define HIDDEN 2048
#define INTER 1024
#define NEXP 64
#define TOPK 8
#define NTOK 512

#define MT 96                  // M tile rows (6 x 16)
#define ROWB 80                // LDS row stride bytes (32 bf16 = 64B + 16B pad)
#define WROWS 256              // W^T rows per buffer (128 gate + 128 up | 256 down)
#define WTB (WROWS * ROWB)     // 20480
#define XOFF WTB
#define BUFB (WTB + MT * ROWB) // 28160; x2 = 56320 B LDS -> 2 blocks/CU
#define AWS_ROWS (NTOK * TOPK + 128)

typedef float floatx4 __attribute__((ext_vector_type(4)));
typedef short shortx8 __attribute__((ext_vector_type(8)));

__device__ __forceinline__ unsigned short bfbits(float f) {
    union { __hip_bfloat16 h; unsigned short u; } c;
    c.h = __float2bfloat16(f);
    return c.u;
}
// pack 4 floats (k-ascending) -> 8B of bf16, k-ascending in memory
__device__ __forceinline__ uint2 pack4(float a, float b, float c, float d) {
    uint2 r;
    r.x = ((unsigned)bfbits(b) << 16) | (unsigned)bfbits(a);
    r.y = ((unsigned)bfbits(d) << 16) | (unsigned)bfbits(c);
    return r;
}

// ---------------- Router + top-8 + softmax + x->bf16 ----------------
// 128 blocks x 256 thr, 4 tokens/block (1 per wave). w_router staged through
// LDS in 64-row chunks shared by the 4 waves: wr HBM/L3 traffic 256MB -> 64MB.
// Per-token fp32 accumulation order identical to prior rounds (a_j sums
// d = j mod 4, ascending) so top-k selection is bit-stable.
__global__ __launch_bounds__(256) void router_topk_kernel(
    const float* __restrict__ x, const float* __restrict__ wr,
    int* __restrict__ topk_idx, float* __restrict__ gates,
    __hip_bfloat16* __restrict__ xbf) {
    const int b4 = blockIdx.x * 4;
    const int tid = threadIdx.x;
    const int lane = tid & 63, w = tid >> 6;
    __shared__ float sx[4 * HIDDEN];       // 32 KB
    __shared__ float wrs[64 * NEXP];       // 16 KB

    const float* xb = x + (size_t)b4 * HIDDEN;
    __hip_bfloat16* xbb = xbf + (size_t)b4 * HIDDEN;
#pragma unroll
    for (int i = 0; i < 8; ++i) {
        int s = i * 256 + tid;
        float4 v = *(const float4*)(xb + s * 4);
        *(float4*)&sx[s * 4] = v;
        ((uint2*)xbb)[s] = pack4(v.x, v.y, v.z, v.w);
    }
    __syncthreads();

    float a0 = 0.f, a1 = 0.f, a2 = 0.f, a3 = 0.f;
    for (int c = 0; c < HIDDEN / 64; ++c) {
#pragma unroll
        for (int j = 0; j < 4; ++j)
            *(float4*)&wrs[tid * 16 + j * 4] =
                *(const float4*)(wr + c * 64 * NEXP + tid * 16 + j * 4);
        __syncthreads();
        const float* sxw = &sx[w * HIDDEN + c * 64];
#pragma unroll
        for (int dd = 0; dd < 64; dd += 4) {
            a0 = fmaf(sxw[dd + 0], wrs[(dd + 0) * NEXP + lane], a0);
            a1 = fmaf(sxw[dd + 1], wrs[(dd + 1) * NEXP + lane], a1);
            a2 = fmaf(sxw[dd + 2], wrs[(dd + 2) * NEXP + lane], a2);
            a3 = fmaf(sxw[dd + 3], wrs[(dd + 3) * NEXP + lane], a3);
        }
        __syncthreads();
    }
    float cur = (a0 + a1) + (a2 + a3);

    const int t = b4 + w;
    float topv[TOPK];
    int topi[TOPK];
#pragma unroll
    for (int k = 0; k < TOPK; ++k) {
        float bv = cur;
        int bi = lane;
#pragma unroll
        for (int off = 32; off > 0; off >>= 1) {
            float ov = __shfl_xor(bv, off, 64);
            int oi = __shfl_xor(bi, off, 64);
            if (ov > bv || (ov == bv && oi < bi)) { bv = ov; bi = oi; }
        }
        topv[k] = bv;
        topi[k] = bi;
        if (lane == bi) cur = -INFINITY;
    }
    if (lane == 0) {
        float m = topv[0];
        float ex[TOPK], s = 0.f;
#pragma unroll
        for (int k = 0; k < TOPK; ++k) { ex[k] = __expf(topv[k] - m); s += ex[k]; }
        float inv = 1.f / s;
#pragma unroll
        for (int k = 0; k < TOPK; ++k) {
            gates[t * TOPK + k] = ex[k] * inv;
            topk_idx[t * TOPK + k] = topi[k];
        }
    }
}

// ---------------- Deterministic bucket build ----------------
__global__ void build_buckets_kernel(const int* __restrict__ topk_idx,
                                     const float* __restrict__ gates,
                                     int* __restrict__ bucket_tok,
                                     float* __restrict__ bucket_gate,
                                     int* __restrict__ count) {
    const int e = blockIdx.x;
    const int tid = threadIdx.x;
    __shared__ int scan[256];
    const int t0 = tid * 2;
    int f0 = 0, f1 = 0;
    float g0 = 0.f, g1 = 0.f;
#pragma unroll
    for (int k = 0; k < TOPK; ++k) {
        if (topk_idx[t0 * TOPK + k] == e) { f0 = 1; g0 = gates[t0 * TOPK + k]; }
        if (topk_idx[(t0 + 1) * TOPK + k] == e) { f1 = 1; g1 = gates[(t0 + 1) * TOPK + k]; }
    }
    int s = f0 + f1;
    scan[tid] = s;
    __syncthreads();
    for (int off = 1; off < 256; off <<= 1) {
        int add = (tid >= off) ? scan[tid - off] : 0;
        __syncthreads();
        scan[tid] += add;
        __syncthreads();
    }
    int excl = scan[tid] - s;
    if (f0) { bucket_tok[e * NTOK + excl] = t0; bucket_gate[e * NTOK + excl] = g0; }
    if (f1) { bucket_tok[e * NTOK + excl + f0] = t0 + 1; bucket_gate[e * NTOK + excl + f0] = g1; }
    if (tid == 255) count[e] = scan[255];
}

// step macro: write bank -> LDS buf, counted wait (banks k+1,k+2 stay in
// flight via reg-dependence vmcnt), barrier, re-issue bank 3 steps ahead,
// compute, barrier. Bank rotation mod 3, buffer mod 2, fully static.
#define GEMM_STEP(BUFOFF, WB, X0, X1, NKT, KTN_)                        \
    do {                                                                \
        writeLDS(smem + (BUFOFF), WB, X0, X1);                          \
        asm volatile("s_waitcnt lgkmcnt(0)" ::: "memory");              \
        __builtin_amdgcn_s_barrier();                                   \
        if ((NKT) < (KTN_)) issue(WB, X0, X1, (NKT));                   \
        compute(smem + (BUFOFF));                                       \
        __builtin_amdgcn_s_barrier();                                   \
    } while (0)

// ---------------- gateup (wide loads + depth-3 prefetch + 2 blk/CU) ----------------
// grid 512: e = bid&63 (expert -> XCD e%8), chunk = bid>>6 covers 128 gate +
// 128 up cols. Staging decode and all math verbatim from R10 (verified);
// only the prefetch depth changed 2 -> 3 (two-phase lookahead).
__global__ __launch_bounds__(256, 2) void gateup_mfma(
    const __hip_bfloat16* __restrict__ xbf, const float* __restrict__ wg,
    const float* __restrict__ wu, const int* __restrict__ bucket_tok,
    const float* __restrict__ bucket_gate, const int* __restrict__ count,
    __hip_bfloat16* __restrict__ Aws) {
    const int e = blockIdx.x & 63;
    const int c0 = (blockIdx.x >> 6) * 128;
    __shared__ char smem[2 * BUFB] __attribute__((aligned(16)));
    __shared__ int base_sm;

    const int tid = threadIdx.x;
    const int n = count[e];
    if (tid < 64) {
        int cv = count[tid];
        int inc = cv;
#pragma unroll
        for (int off = 1; off < 64; off <<= 1) {
            int v = __shfl_up(inc, off, 64);
            if (tid >= off) inc += v;
        }
        if (tid == e) base_sm = inc - cv;
    }
    __syncthreads();
    const int b0 = base_sm;
    if (n == 0) return;

    const int lane = tid & 63, w = tid >> 6;
    const int q = lane >> 4, r16 = lane & 15;

    const int m_ = tid >> 7;
    const int s_ = tid & 127;
    const int c4 = (s_ & 31) * 4;
    const int kb = (s_ >> 5) * 8;
    const float* wsrc = ((m_ == 0) ? wg : wu) + (size_t)e * HIDDEN * INTER
                        + (size_t)kb * INTER + c0 + c4;
    const unsigned wldso = (unsigned)((m_ * 128 + c4) * ROWB + kb * 2);

    const int xr0 = tid >> 2, xc0 = tid & 3;
    const int slot1 = 256 + tid;
    const int xr1 = slot1 >> 2, xc1 = slot1 & 3;
    const bool x1v = tid < 128;
    const unsigned xldso0 = (unsigned)(XOFF + xr0 * ROWB + xc0 * 16);
    const unsigned xldso1 = (unsigned)(XOFF + xr1 * ROWB + xc1 * 16);

    for (int m0 = 0; m0 < n; m0 += MT) {
        int p0 = m0 + xr0;
        int tk0 = (p0 < n) ? bucket_tok[e * NTOK + p0] : 0;
        const __hip_bfloat16* xp0 = xbf + (size_t)tk0 * HIDDEN + xc0 * 8;
        int p1 = m0 + xr1;
        int tk1 = (x1v && p1 < n) ? bucket_tok[e * NTOK + p1] : 0;
        const __hip_bfloat16* xp1 = xbf + (size_t)tk1 * HIDDEN + xc1 * 8;

        floatx4 acc[6][4];
#pragma unroll
        for (int ms = 0; ms < 6; ++ms)
#pragma unroll
            for (int s = 0; s < 4; ++s) acc[ms][s] = (floatx4){0.f, 0.f, 0.f, 0.f};

        float4 wA[8], wB[8], wC[8];
        uint4 xA0, xA1, xB0, xB1, xC0v, xC1v;

        auto issue = [&](float4 (&wv)[8], uint4& x0, uint4& x1, int kt) {
            const float* p = wsrc + (size_t)kt * 32 * INTER;
#pragma unroll
            for (int j = 0; j < 8; ++j) wv[j] = *(const float4*)(p + (size_t)j * INTER);
            x0 = *(const uint4*)(xp0 + kt * 32);
            if (x1v) x1 = *(const uint4*)(xp1 + kt * 32);
        };
        auto writeLDS = [&](char* buf, float4 (&wv)[8], uint4& x0, uint4& x1) {
#pragma unroll
            for (int i = 0; i < 4; ++i) {
                uint2 lo = pack4(wv[0][i], wv[1][i], wv[2][i], wv[3][i]);
                uint2 hi = pack4(wv[4][i], wv[5][i], wv[6][i], wv[7][i]);
                uint4 v; v.x = lo.x; v.y = lo.y; v.z = hi.x; v.w = hi.y;
                *(uint4*)(buf + wldso + i * ROWB) = v;
            }
            *(uint4*)(buf + xldso0) = x0;
            if (x1v) *(uint4*)(buf + xldso1) = x1;
        };
        auto compute = [&](const char* buf) {
            shortx8 bfr[4];
#pragma unroll
            for (int s = 0; s < 2; ++s) {
                bfr[s]     = *(const shortx8*)(buf + ((2 * w + s) * 16 + r16) * ROWB + q * 16);
                bfr[2 + s] = *(const shortx8*)(buf + ((128 + (2 * w + s) * 16) + r16) * ROWB + q * 16);
            }
            shortx8 afr[6];
#pragma unroll
            for (int ms = 0; ms < 6; ++ms)
                afr[ms] = *(const shortx8*)(buf + XOFF + (ms * 16 + r16) * ROWB + q * 16);
#pragma unroll
            for (int ms = 0; ms < 6; ++ms)
#pragma unroll
                for (int s = 0; s < 4; ++s)
                    acc[ms][s] = __builtin_amdgcn_mfma_f32_16x16x32_bf16(afr[ms], bfr[s], acc[ms][s], 0, 0, 0);
        };

        const int KTN = HIDDEN / 32;   // 64
        issue(wA, xA0, xA1, 0);
        issue(wB, xB0, xB1, 1);
        issue(wC, xC0v, xC1v, 2);
        for (int s6 = 0; s6 < 60; s6 += 6) {
            GEMM_STEP(0,    wA, xA0,  xA1,  s6 + 3, KTN);
            GEMM_STEP(BUFB, wB, xB0,  xB1,  s6 + 4, KTN);
            GEMM_STEP(0,    wC, xC0v, xC1v, s6 + 5, KTN);
            GEMM_STEP(BUFB, wA, xA0,  xA1,  s6 + 6, KTN);
            GEMM_STEP(0,    wB, xB0,  xB1,  s6 + 7, KTN);
            GEMM_STEP(BUFB, wC, xC0v, xC1v, s6 + 8, KTN);
        }
        GEMM_STEP(0,    wA, xA0,  xA1,  63, KTN);   // step 60 issues tile 63 -> bank A
        GEMM_STEP(BUFB, wB, xB0,  xB1,  64, KTN);   // step 61
        GEMM_STEP(0,    wC, xC0v, xC1v, 64, KTN);   // step 62
        GEMM_STEP(BUFB, wA, xA0,  xA1,  64, KTN);   // step 63 (tile 63)

        // epilogue: A = silu(h) * u * gate, bf16  (C: col=lane&15, row=4q+reg)
#pragma unroll
        for (int ms = 0; ms < 6; ++ms) {
#pragma unroll
            for (int j = 0; j < 2; ++j) {
                floatx4 h4 = acc[ms][j], u4 = acc[ms][j + 2];
#pragma unroll
                for (int rr = 0; rr < 4; ++rr) {
                    int ml = ms * 16 + 4 * q + rr;
                    int p = m0 + ml;
                    if (p < n) {
                        float gt = bucket_gate[e * NTOK + p];
                        float hv = h4[rr];
                        float av = hv / (1.f + __expf(-hv)) * u4[rr] * gt;
                        int col = c0 + (2 * w + j) * 16 + r16;
                        Aws[(size_t)(b0 + p) * INTER + col] = __float2bfloat16(av);
                    }
                }
            }
        }
    }
}

// ---------------- down (wide loads + depth-3 prefetch + 2 blk/CU) ----------------
// grid 512: e = bid&63, chunk = bid>>6 covers 256 out cols.
__global__ __launch_bounds__(256, 2) void down_mfma(
    const __hip_bfloat16* __restrict__ Aws, const float* __restrict__ wd,
    const int* __restrict__ bucket_tok, const int* __restrict__ count,
    float* __restrict__ out) {
    const int e = blockIdx.x & 63;
    const int c0 = (blockIdx.x >> 6) * 256;
    __shared__ char smem[2 * BUFB] __attribute__((aligned(16)));
    __shared__ int base_sm;

    const int tid = threadIdx.x;
    const int n = count[e];
    if (tid < 64) {
        int cv = count[tid];
        int inc = cv;
#pragma unroll
        for (int off = 1; off < 64; off <<= 1) {
            int v = __shfl_up(inc, off, 64);
            if (tid >= off) inc += v;
        }
        if (tid == e) base_sm = inc - cv;
    }
    __syncthreads();
    const int b0 = base_sm;
    if (n == 0) return;

    const int lane = tid & 63, w = tid >> 6;
    const int q = lane >> 4, r16 = lane & 15;

    const int c4 = (tid & 63) * 4;
    const int kb = (tid >> 6) * 8;
    const float* wsrc = wd + (size_t)e * INTER * HIDDEN + (size_t)kb * HIDDEN + c0 + c4;
    const unsigned wldso = (unsigned)(c4 * ROWB + kb * 2);

    const int xr0 = tid >> 2, xc0 = tid & 3;
    const int slot1 = 256 + tid;
    const int xr1 = slot1 >> 2, xc1 = slot1 & 3;
    const bool x1v = tid < 128;
    const unsigned xldso0 = (unsigned)(XOFF + xr0 * ROWB + xc0 * 16);
    const unsigned xldso1 = (unsigned)(XOFF + xr1 * ROWB + xc1 * 16);

    for (int m0 = 0; m0 < n; m0 += MT) {
        const __hip_bfloat16* ap0 = Aws + (size_t)(b0 + m0 + xr0) * INTER + xc0 * 8;
        const __hip_bfloat16* ap1 = Aws + (size_t)(b0 + m0 + xr1) * INTER + xc1 * 8;

        floatx4 acc[6][4];
#pragma unroll
        for (int ms = 0; ms < 6; ++ms)
#pragma unroll
            for (int s = 0; s < 4; ++s) acc[ms][s] = (floatx4){0.f, 0.f, 0.f, 0.f};

        float4 wA[8], wB[8], wC[8];
        uint4 xA0, xA1, xB0, xB1, xC0v, xC1v;

        auto issue = [&](float4 (&wv)[8], uint4& x0, uint4& x1, int kt) {
            const float* p = wsrc + (size_t)kt * 32 * HIDDEN;
#pragma unroll
            for (int j = 0; j < 8; ++j) wv[j] = *(const float4*)(p + (size_t)j * HIDDEN);
            x0 = *(const uint4*)(ap0 + kt * 32);
            if (x1v) x1 = *(const uint4*)(ap1 + kt * 32);
        };
        auto writeLDS = [&](char* buf, float4 (&wv)[8], uint4& x0, uint4& x1) {
#pragma unroll
            for (int i = 0; i < 4; ++i) {
                uint2 lo = pack4(wv[0][i], wv[1][i], wv[2][i], wv[3][i]);
                uint2 hi = pack4(wv[4][i], wv[5][i], wv[6][i], wv[7][i]);
                uint4 v; v.x = lo.x; v.y = lo.y; v.z = hi.x; v.w = hi.y;
                *(uint4*)(buf + wldso + i * ROWB) = v;
            }
            *(uint4*)(buf + xldso0) = x0;
            if (x1v) *(uint4*)(buf + xldso1) = x1;
        };
        auto compute = [&](const char* buf) {
            shortx8 bfr[4];
#pragma unroll
            for (int s = 0; s < 4; ++s)
                bfr[s] = *(const shortx8*)(buf + ((4 * w + s) * 16 + r16) * ROWB + q * 16);
            shortx8 afr[6];
#pragma unroll
            for (int ms = 0; ms < 6; ++ms)
                afr[ms] = *(const shortx8*)(buf + XOFF + (ms * 16 + r16) * ROWB + q * 16);
#pragma unroll
            for (int ms = 0; ms < 6; ++ms)
#pragma unroll
                for (int s = 0; s < 4; ++s)
                    acc[ms][s] = __builtin_amdgcn_mfma_f32_16x16x32_bf16(afr[ms], bfr[s], acc[ms][s], 0, 0, 0);
        };

        const int KTN = INTER / 32;    // 32
        issue(wA, xA0, xA1, 0);
        issue(wB, xB0, xB1, 1);
        issue(wC, xC0v, xC1v, 2);
        for (int s6 = 0; s6 < 30; s6 += 6) {
            GEMM_STEP(0,    wA, xA0,  xA1,  s6 + 3, KTN);
            GEMM_STEP(BUFB, wB, xB0,  xB1,  s6 + 4, KTN);
            GEMM_STEP(0,    wC, xC0v, xC1v, s6 + 5, KTN);
            GEMM_STEP(BUFB, wA, xA0,  xA1,  s6 + 6, KTN);
            GEMM_STEP(0,    wB, xB0,  xB1,  s6 + 7, KTN);
            GEMM_STEP(BUFB, wC, xC0v, xC1v, s6 + 8, KTN);
        }
        GEMM_STEP(0,    wA, xA0,  xA1,  32, KTN);   // step 30 (tile 30)
        GEMM_STEP(BUFB, wB, xB0,  xB1,  32, KTN);   // step 31 (tile 31)

#pragma unroll
        for (int ms = 0; ms < 6; ++ms) {
#pragma unroll
            for (int rr = 0; rr < 4; ++rr) {
                int ml = ms * 16 + 4 * q + rr;
                int p = m0 + ml;
                if (p < n) {
                    int tok = bucket_tok[e * NTOK + p];
                    float* orow = out + (size_t)tok * HIDDEN;
#pragma unroll
                    for (int s = 0; s < 4; ++s) {
                        int col = c0 + (4 * w + s) * 16 + r16;
                        unsafeAtomicAdd(&orow[col], acc[ms][s][rr]);
                    }
                }
            }
        }
    }
}

extern "C" void kernel_launch(void* const* d_in, const int* in_sizes, int n_in,
                              void* d_out, int out_size, void* d_ws, size_t ws_size,
                              hipStream_t stream) {
    const float* x = (const float*)d_in[0];
    const float* wr = (const float*)d_in[1];
    const float* wg = (const float*)d_in[2];
    const float* wu = (const float*)d_in[3];
    const float* wd = (const float*)d_in[4];
    float* out = (float*)d_out;

    char* ws = (char*)d_ws;
    size_t off = 0;
    auto alloc = [&](size_t bytes) {
        void* p = ws + off;
        off = (off + bytes + 255) & ~(size_t)255;
        return p;
    };
    int* topk_idx = (int*)alloc(NTOK * TOPK * sizeof(int));
    float* gates = (float*)alloc(NTOK * TOPK * sizeof(float));
    int* bucket_tok = (int*)alloc(NEXP * NTOK * sizeof(int));
    float* bucket_gate = (float*)alloc(NEXP * NTOK * sizeof(float));
    int* count = (int*)alloc(NEXP * sizeof(int));
    __hip_bfloat16* Aws = (__hip_bfloat16*)alloc((size_t)AWS_ROWS * INTER * sizeof(__hip_bfloat16));
    __hip_bfloat16* xbf = (__hip_bfloat16*)alloc((size_t)NTOK * HIDDEN * sizeof(__hip_bfloat16));
    (void)ws_size;

    hipMemsetAsync(d_out, 0, (size_t)NTOK * HIDDEN * sizeof(float), stream);

    router_topk_kernel<<<NTOK / 4, 256, 0, stream>>>(x, wr, topk_idx, gates, xbf);
    build_buckets_kernel<<<NEXP, 256, 0, stream>>>(topk_idx, gates, bucket_tok, bucket_gate, count);
    gateup_mfma<<<NEXP * 8, 256, 0, stream>>>(xbf, wg, wu, bucket_tok, bucket_gate, count, Aws);
    down_mfma<<<NEXP * 8, 256, 0, stream>>>(Aws, wd, bucket_tok, count, out);
}

// Round 12
// 408.540 us; speedup vs baseline: 1.6474x; 1.6474x over previous
//
#include <hip/hip_runtime.h>
#include <hip/hip_bf16.h>
#include <math.h>

#define HIDDEN 2048
#define INTER 1024
#define NEXP 64
#define TOPK 8
#define NTOK 512

#define MT 96                  // M tile rows (6 x 16)
#define ROWB 80                // LDS row stride bytes (32 bf16 = 64B + 16B pad)
#define WROWS 256              // W^T rows per buffer (128 gate + 128 up | 256 down)
#define WTB (WROWS * ROWB)     // 20480
#define XOFF WTB
#define BUFB (WTB + MT * ROWB) // 28160; x2 = 56320 B LDS -> 2 blocks/CU
#define AWS_ROWS (NTOK * TOPK + 128)

typedef float floatx4 __attribute__((ext_vector_type(4)));
typedef short shortx8 __attribute__((ext_vector_type(8)));

__device__ __forceinline__ unsigned short bfbits(float f) {
    union { __hip_bfloat16 h; unsigned short u; } c;
    c.h = __float2bfloat16(f);
    return c.u;
}
// pack 4 floats (k-ascending) -> 8B of bf16, k-ascending in memory
__device__ __forceinline__ uint2 pack4(float a, float b, float c, float d) {
    uint2 r;
    r.x = ((unsigned)bfbits(b) << 16) | (unsigned)bfbits(a);
    r.y = ((unsigned)bfbits(d) << 16) | (unsigned)bfbits(c);
    return r;
}

// ---------------- Router + top-8 + softmax + x->bf16 ----------------
// 128 blocks x 256 thr, 4 tokens/block (1 per wave). w_router staged through
// LDS in 64-row chunks shared by the 4 waves: wr L2/L3 traffic 256MB -> 64MB.
// Per-token fp32 accumulation order identical to prior rounds (a_j sums
// d = j mod 4, ascending) so top-k selection is bit-stable. [R11-verified]
__global__ __launch_bounds__(256) void router_topk_kernel(
    const float* __restrict__ x, const float* __restrict__ wr,
    int* __restrict__ topk_idx, float* __restrict__ gates,
    __hip_bfloat16* __restrict__ xbf) {
    const int b4 = blockIdx.x * 4;
    const int tid = threadIdx.x;
    const int lane = tid & 63, w = tid >> 6;
    __shared__ float sx[4 * HIDDEN];       // 32 KB
    __shared__ float wrs[64 * NEXP];       // 16 KB

    const float* xb = x + (size_t)b4 * HIDDEN;
    __hip_bfloat16* xbb = xbf + (size_t)b4 * HIDDEN;
#pragma unroll
    for (int i = 0; i < 8; ++i) {
        int s = i * 256 + tid;
        float4 v = *(const float4*)(xb + s * 4);
        *(float4*)&sx[s * 4] = v;
        ((uint2*)xbb)[s] = pack4(v.x, v.y, v.z, v.w);
    }
    __syncthreads();

    float a0 = 0.f, a1 = 0.f, a2 = 0.f, a3 = 0.f;
    for (int c = 0; c < HIDDEN / 64; ++c) {
#pragma unroll
        for (int j = 0; j < 4; ++j)
            *(float4*)&wrs[tid * 16 + j * 4] =
                *(const float4*)(wr + c * 64 * NEXP + tid * 16 + j * 4);
        __syncthreads();
        const float* sxw = &sx[w * HIDDEN + c * 64];
#pragma unroll
        for (int dd = 0; dd < 64; dd += 4) {
            a0 = fmaf(sxw[dd + 0], wrs[(dd + 0) * NEXP + lane], a0);
            a1 = fmaf(sxw[dd + 1], wrs[(dd + 1) * NEXP + lane], a1);
            a2 = fmaf(sxw[dd + 2], wrs[(dd + 2) * NEXP + lane], a2);
            a3 = fmaf(sxw[dd + 3], wrs[(dd + 3) * NEXP + lane], a3);
        }
        __syncthreads();
    }
    float cur = (a0 + a1) + (a2 + a3);

    const int t = b4 + w;
    float topv[TOPK];
    int topi[TOPK];
#pragma unroll
    for (int k = 0; k < TOPK; ++k) {
        float bv = cur;
        int bi = lane;
#pragma unroll
        for (int off = 32; off > 0; off >>= 1) {
            float ov = __shfl_xor(bv, off, 64);
            int oi = __shfl_xor(bi, off, 64);
            if (ov > bv || (ov == bv && oi < bi)) { bv = ov; bi = oi; }
        }
        topv[k] = bv;
        topi[k] = bi;
        if (lane == bi) cur = -INFINITY;
    }
    if (lane == 0) {
        float m = topv[0];
        float ex[TOPK], s = 0.f;
#pragma unroll
        for (int k = 0; k < TOPK; ++k) { ex[k] = __expf(topv[k] - m); s += ex[k]; }
        float inv = 1.f / s;
#pragma unroll
        for (int k = 0; k < TOPK; ++k) {
            gates[t * TOPK + k] = ex[k] * inv;
            topk_idx[t * TOPK + k] = topi[k];
        }
    }
}

// ---------------- Deterministic bucket build ----------------
__global__ void build_buckets_kernel(const int* __restrict__ topk_idx,
                                     const float* __restrict__ gates,
                                     int* __restrict__ bucket_tok,
                                     float* __restrict__ bucket_gate,
                                     int* __restrict__ count) {
    const int e = blockIdx.x;
    const int tid = threadIdx.x;
    __shared__ int scan[256];
    const int t0 = tid * 2;
    int f0 = 0, f1 = 0;
    float g0 = 0.f, g1 = 0.f;
#pragma unroll
    for (int k = 0; k < TOPK; ++k) {
        if (topk_idx[t0 * TOPK + k] == e) { f0 = 1; g0 = gates[t0 * TOPK + k]; }
        if (topk_idx[(t0 + 1) * TOPK + k] == e) { f1 = 1; g1 = gates[(t0 + 1) * TOPK + k]; }
    }
    int s = f0 + f1;
    scan[tid] = s;
    __syncthreads();
    for (int off = 1; off < 256; off <<= 1) {
        int add = (tid >= off) ? scan[tid - off] : 0;
        __syncthreads();
        scan[tid] += add;
        __syncthreads();
    }
    int excl = scan[tid] - s;
    if (f0) { bucket_tok[e * NTOK + excl] = t0; bucket_gate[e * NTOK + excl] = g0; }
    if (f1) { bucket_tok[e * NTOK + excl + f0] = t0 + 1; bucket_gate[e * NTOK + excl + f0] = g1; }
    if (tid == 255) count[e] = scan[255];
}

// ---------------- gateup (wide loads + reg-pack + 2 blk/CU) [R10-verified] ----------------
// grid 512: e = bid&63 (expert -> XCD e%8), chunk = bid>>6 covers 128 gate +
// 128 up cols. 256 threads = 4 waves, 2 blocks/CU. Depth-2 register prefetch.
__global__ __launch_bounds__(256, 2) void gateup_mfma(
    const __hip_bfloat16* __restrict__ xbf, const float* __restrict__ wg,
    const float* __restrict__ wu, const int* __restrict__ bucket_tok,
    const float* __restrict__ bucket_gate, const int* __restrict__ count,
    __hip_bfloat16* __restrict__ Aws) {
    const int e = blockIdx.x & 63;
    const int c0 = (blockIdx.x >> 6) * 128;
    __shared__ char smem[2 * BUFB] __attribute__((aligned(16)));
    __shared__ int base_sm;

    const int tid = threadIdx.x;
    const int n = count[e];
    if (tid < 64) {                    // base[e] via shfl scan
        int cv = count[tid];
        int inc = cv;
#pragma unroll
        for (int off = 1; off < 64; off <<= 1) {
            int v = __shfl_up(inc, off, 64);
            if (tid >= off) inc += v;
        }
        if (tid == e) base_sm = inc - cv;
    }
    __syncthreads();
    const int b0 = base_sm;
    if (n == 0) return;

    const int lane = tid & 63, w = tid >> 6;
    const int q = lane >> 4, r16 = lane & 15;

    const int m_ = tid >> 7;           // 0 gate, 1 up
    const int s_ = tid & 127;
    const int c4 = (s_ & 31) * 4;      // col group
    const int kb = (s_ >> 5) * 8;      // k base (0,8,16,24)
    const float* wsrc = ((m_ == 0) ? wg : wu) + (size_t)e * HIDDEN * INTER
                        + (size_t)kb * INTER + c0 + c4;
    const unsigned wldso = (unsigned)((m_ * 128 + c4) * ROWB + kb * 2);

    const int xr0 = tid >> 2, xc0 = tid & 3;
    const int slot1 = 256 + tid;
    const int xr1 = slot1 >> 2, xc1 = slot1 & 3;
    const bool x1v = tid < 128;
    const unsigned xldso0 = (unsigned)(XOFF + xr0 * ROWB + xc0 * 16);
    const unsigned xldso1 = (unsigned)(XOFF + xr1 * ROWB + xc1 * 16);

    for (int m0 = 0; m0 < n; m0 += MT) {
        int p0 = m0 + xr0;
        int tk0 = (p0 < n) ? bucket_tok[e * NTOK + p0] : 0;
        const __hip_bfloat16* xp0 = xbf + (size_t)tk0 * HIDDEN + xc0 * 8;
        int p1 = m0 + xr1;
        int tk1 = (x1v && p1 < n) ? bucket_tok[e * NTOK + p1] : 0;
        const __hip_bfloat16* xp1 = xbf + (size_t)tk1 * HIDDEN + xc1 * 8;

        floatx4 acc[6][4];
#pragma unroll
        for (int ms = 0; ms < 6; ++ms)
#pragma unroll
            for (int s = 0; s < 4; ++s) acc[ms][s] = (floatx4){0.f, 0.f, 0.f, 0.f};

        float4 wA[8], wB[8];
        uint4 xA0, xA1, xB0, xB1;

        auto issueA = [&](int kt) {
            const float* p = wsrc + (size_t)kt * 32 * INTER;
#pragma unroll
            for (int j = 0; j < 8; ++j) wA[j] = *(const float4*)(p + (size_t)j * INTER);
            xA0 = *(const uint4*)(xp0 + kt * 32);
            if (x1v) xA1 = *(const uint4*)(xp1 + kt * 32);
        };
        auto issueB = [&](int kt) {
            const float* p = wsrc + (size_t)kt * 32 * INTER;
#pragma unroll
            for (int j = 0; j < 8; ++j) wB[j] = *(const float4*)(p + (size_t)j * INTER);
            xB0 = *(const uint4*)(xp0 + kt * 32);
            if (x1v) xB1 = *(const uint4*)(xp1 + kt * 32);
        };
        auto writeLDS = [&](char* buf, float4 (&wv)[8], uint4& x0, uint4& x1) {
#pragma unroll
            for (int i = 0; i < 4; ++i) {
                uint2 lo = pack4(wv[0][i], wv[1][i], wv[2][i], wv[3][i]);
                uint2 hi = pack4(wv[4][i], wv[5][i], wv[6][i], wv[7][i]);
                uint4 v; v.x = lo.x; v.y = lo.y; v.z = hi.x; v.w = hi.y;
                *(uint4*)(buf + wldso + i * ROWB) = v;
            }
            *(uint4*)(buf + xldso0) = x0;
            if (x1v) *(uint4*)(buf + xldso1) = x1;
        };
        auto compute = [&](const char* buf) {
            shortx8 bfr[4];
#pragma unroll
            for (int s = 0; s < 2; ++s) {
                bfr[s]     = *(const shortx8*)(buf + ((2 * w + s) * 16 + r16) * ROWB + q * 16);
                bfr[2 + s] = *(const shortx8*)(buf + ((128 + (2 * w + s) * 16) + r16) * ROWB + q * 16);
            }
            shortx8 afr[6];
#pragma unroll
            for (int ms = 0; ms < 6; ++ms)
                afr[ms] = *(const shortx8*)(buf + XOFF + (ms * 16 + r16) * ROWB + q * 16);
#pragma unroll
            for (int ms = 0; ms < 6; ++ms)
#pragma unroll
                for (int s = 0; s < 4; ++s)
                    acc[ms][s] = __builtin_amdgcn_mfma_f32_16x16x32_bf16(afr[ms], bfr[s], acc[ms][s], 0, 0, 0);
        };

        issueA(0);
        issueB(1);
        const int KTN = HIDDEN / 32;
        for (int kt2 = 0; kt2 < KTN / 2; ++kt2) {
            const int kt = 2 * kt2;
            writeLDS(smem, wA, xA0, xA1);                 // waits vmcnt on bank A only
            asm volatile("s_waitcnt lgkmcnt(0)" ::: "memory");
            __builtin_amdgcn_s_barrier();
            if (kt + 2 < KTN) issueA(kt + 2);             // depth-2 prefetch
            compute(smem);
            __builtin_amdgcn_s_barrier();
            writeLDS(smem + BUFB, wB, xB0, xB1);
            asm volatile("s_waitcnt lgkmcnt(0)" ::: "memory");
            __builtin_amdgcn_s_barrier();
            if (kt + 3 < KTN) issueB(kt + 3);
            compute(smem + BUFB);
            __builtin_amdgcn_s_barrier();
        }

        // epilogue: A = silu(h) * u * gate, bf16  (C: col=lane&15, row=4q+reg)
#pragma unroll
        for (int ms = 0; ms < 6; ++ms) {
#pragma unroll
            for (int j = 0; j < 2; ++j) {
                floatx4 h4 = acc[ms][j], u4 = acc[ms][j + 2];
#pragma unroll
                for (int rr = 0; rr < 4; ++rr) {
                    int ml = ms * 16 + 4 * q + rr;
                    int p = m0 + ml;
                    if (p < n) {
                        float gt = bucket_gate[e * NTOK + p];
                        float hv = h4[rr];
                        float av = hv / (1.f + __expf(-hv)) * u4[rr] * gt;
                        int col = c0 + (2 * w + j) * 16 + r16;
                        Aws[(size_t)(b0 + p) * INTER + col] = __float2bfloat16(av);
                    }
                }
            }
        }
    }
}

// ---------------- down (wide loads + reg-pack + 2 blk/CU) [R10-verified] ----------------
// grid 512: e = bid&63, chunk = bid>>6 covers 256 out cols.
__global__ __launch_bounds__(256, 2) void down_mfma(
    const __hip_bfloat16* __restrict__ Aws, const float* __restrict__ wd,
    const int* __restrict__ bucket_tok, const int* __restrict__ count,
    float* __restrict__ out) {
    const int e = blockIdx.x & 63;
    const int c0 = (blockIdx.x >> 6) * 256;
    __shared__ char smem[2 * BUFB] __attribute__((aligned(16)));
    __shared__ int base_sm;

    const int tid = threadIdx.x;
    const int n = count[e];
    if (tid < 64) {
        int cv = count[tid];
        int inc = cv;
#pragma unroll
        for (int off = 1; off < 64; off <<= 1) {
            int v = __shfl_up(inc, off, 64);
            if (tid >= off) inc += v;
        }
        if (tid == e) base_sm = inc - cv;
    }
    __syncthreads();
    const int b0 = base_sm;
    if (n == 0) return;

    const int lane = tid & 63, w = tid >> 6;
    const int q = lane >> 4, r16 = lane & 15;

    const int c4 = (tid & 63) * 4;
    const int kb = (tid >> 6) * 8;
    const float* wsrc = wd + (size_t)e * INTER * HIDDEN + (size_t)kb * HIDDEN + c0 + c4;
    const unsigned wldso = (unsigned)(c4 * ROWB + kb * 2);

    const int xr0 = tid >> 2, xc0 = tid & 3;
    const int slot1 = 256 + tid;
    const int xr1 = slot1 >> 2, xc1 = slot1 & 3;
    const bool x1v = tid < 128;
    const unsigned xldso0 = (unsigned)(XOFF + xr0 * ROWB + xc0 * 16);
    const unsigned xldso1 = (unsigned)(XOFF + xr1 * ROWB + xc1 * 16);

    for (int m0 = 0; m0 < n; m0 += MT) {
        const __hip_bfloat16* ap0 = Aws + (size_t)(b0 + m0 + xr0) * INTER + xc0 * 8;
        const __hip_bfloat16* ap1 = Aws + (size_t)(b0 + m0 + xr1) * INTER + xc1 * 8;

        floatx4 acc[6][4];
#pragma unroll
        for (int ms = 0; ms < 6; ++ms)
#pragma unroll
            for (int s = 0; s < 4; ++s) acc[ms][s] = (floatx4){0.f, 0.f, 0.f, 0.f};

        float4 wA[8], wB[8];
        uint4 aA0, aA1, aB0, aB1;

        auto issueA = [&](int kt) {
            const float* p = wsrc + (size_t)kt * 32 * HIDDEN;
#pragma unroll
            for (int j = 0; j < 8; ++j) wA[j] = *(const float4*)(p + (size_t)j * HIDDEN);
            aA0 = *(const uint4*)(ap0 + kt * 32);
            if (x1v) aA1 = *(const uint4*)(ap1 + kt * 32);
        };
        auto issueB = [&](int kt) {
            const float* p = wsrc + (size_t)kt * 32 * HIDDEN;
#pragma unroll
            for (int j = 0; j < 8; ++j) wB[j] = *(const float4*)(p + (size_t)j * HIDDEN);
            aB0 = *(const uint4*)(ap0 + kt * 32);
            if (x1v) aB1 = *(const uint4*)(ap1 + kt * 32);
        };
        auto writeLDS = [&](char* buf, float4 (&wv)[8], uint4& a0, uint4& a1) {
#pragma unroll
            for (int i = 0; i < 4; ++i) {
                uint2 lo = pack4(wv[0][i], wv[1][i], wv[2][i], wv[3][i]);
                uint2 hi = pack4(wv[4][i], wv[5][i], wv[6][i], wv[7][i]);
                uint4 v; v.x = lo.x; v.y = lo.y; v.z = hi.x; v.w = hi.y;
                *(uint4*)(buf + wldso + i * ROWB) = v;
            }
            *(uint4*)(buf + xldso0) = a0;
            if (x1v) *(uint4*)(buf + xldso1) = a1;
        };
        auto compute = [&](const char* buf) {
            shortx8 bfr[4];
#pragma unroll
            for (int s = 0; s < 4; ++s)
                bfr[s] = *(const shortx8*)(buf + ((4 * w + s) * 16 + r16) * ROWB + q * 16);
            shortx8 afr[6];
#pragma unroll
            for (int ms = 0; ms < 6; ++ms)
                afr[ms] = *(const shortx8*)(buf + XOFF + (ms * 16 + r16) * ROWB + q * 16);
#pragma unroll
            for (int ms = 0; ms < 6; ++ms)
#pragma unroll
                for (int s = 0; s < 4; ++s)
                    acc[ms][s] = __builtin_amdgcn_mfma_f32_16x16x32_bf16(afr[ms], bfr[s], acc[ms][s], 0, 0, 0);
        };

        issueA(0);
        issueB(1);
        const int KTN = INTER / 32;
        for (int kt2 = 0; kt2 < KTN / 2; ++kt2) {
            const int kt = 2 * kt2;
            writeLDS(smem, wA, aA0, aA1);
            asm volatile("s_waitcnt lgkmcnt(0)" ::: "memory");
            __builtin_amdgcn_s_barrier();
            if (kt + 2 < KTN) issueA(kt + 2);
            compute(smem);
            __builtin_amdgcn_s_barrier();
            writeLDS(smem + BUFB, wB, aB0, aB1);
            asm volatile("s_waitcnt lgkmcnt(0)" ::: "memory");
            __builtin_amdgcn_s_barrier();
            if (kt + 3 < KTN) issueB(kt + 3);
            compute(smem + BUFB);
            __builtin_amdgcn_s_barrier();
        }

#pragma unroll
        for (int ms = 0; ms < 6; ++ms) {
#pragma unroll
            for (int rr = 0; rr < 4; ++rr) {
                int ml = ms * 16 + 4 * q + rr;
                int p = m0 + ml;
                if (p < n) {
                    int tok = bucket_tok[e * NTOK + p];
                    float* orow = out + (size_t)tok * HIDDEN;
#pragma unroll
                    for (int s = 0; s < 4; ++s) {
                        int col = c0 + (4 * w + s) * 16 + r16;
                        unsafeAtomicAdd(&orow[col], acc[ms][s][rr]);
                    }
                }
            }
        }
    }
}

extern "C" void kernel_launch(void* const* d_in, const int* in_sizes, int n_in,
                              void* d_out, int out_size, void* d_ws, size_t ws_size,
                              hipStream_t stream) {
    const float* x = (const float*)d_in[0];
    const float* wr = (const float*)d_in[1];
    const float* wg = (const float*)d_in[2];
    const float* wu = (const float*)d_in[3];
    const float* wd = (const float*)d_in[4];
    float* out = (float*)d_out;

    char* ws = (char*)d_ws;
    size_t off = 0;
    auto alloc = [&](size_t bytes) {
        void* p = ws + off;
        off = (off + bytes + 255) & ~(size_t)255;
        return p;
    };
    int* topk_idx = (int*)alloc(NTOK * TOPK * sizeof(int));
    float* gates = (float*)alloc(NTOK * TOPK * sizeof(float));
    int* bucket_tok = (int*)alloc(NEXP * NTOK * sizeof(int));
    float* bucket_gate = (float*)alloc(NEXP * NTOK * sizeof(float));
    int* count = (int*)alloc(NEXP * sizeof(int));
    __hip_bfloat16* Aws = (__hip_bfloat16*)alloc((size_t)AWS_ROWS * INTER * sizeof(__hip_bfloat16));
    __hip_bfloat16* xbf = (__hip_bfloat16*)alloc((size_t)NTOK * HIDDEN * sizeof(__hip_bfloat16));
    (void)ws_size;

    hipMemsetAsync(d_out, 0, (size_t)NTOK * HIDDEN * sizeof(float), stream);

    router_topk_kernel<<<NTOK / 4, 256, 0, stream>>>(x, wr, topk_idx, gates, xbf);
    build_buckets_kernel<<<NEXP, 256, 0, stream>>>(topk_idx, gates, bucket_tok, bucket_gate, count);
    gateup_mfma<<<NEXP * 8, 256, 0, stream>>>(xbf, wg, wu, bucket_tok, bucket_gate, count, Aws);
    down_mfma<<<NEXP * 8, 256, 0, stream>>>(Aws, wd, bucket_tok, count, out);
}

// Round 13
// 395.269 us; speedup vs baseline: 1.7027x; 1.0336x over previous
//
#include <hip/hip_runtime.h>
#include <hip/hip_bf16.h>
#include <math.h>

#define HIDDEN 2048
#define INTER 1024
#define NEXP 64
#define TOPK 8
#define NTOK 512

#define MT 96                  // M tile rows (6 x 16)
#define ROWB 80                // LDS row stride bytes (32 bf16 = 64B + 16B pad)
#define WROWS 256              // W^T rows per buffer (128 gate + 128 up | 256 down)
#define WTB (WROWS * ROWB)     // 20480
#define XOFF WTB
#define BUFB (WTB + MT * ROWB) // 28160; x2 = 56320 B LDS -> 2 blocks/CU
#define AWS_ROWS (NTOK * TOPK + 128)

typedef float floatx4 __attribute__((ext_vector_type(4)));
typedef short shortx8 __attribute__((ext_vector_type(8)));

__device__ __forceinline__ unsigned short bfbits(float f) {
    union { __hip_bfloat16 h; unsigned short u; } c;
    c.h = __float2bfloat16(f);
    return c.u;
}
// pack 4 floats (k-ascending) -> 8B of bf16, k-ascending in memory
__device__ __forceinline__ uint2 pack4(float a, float b, float c, float d) {
    uint2 r;
    r.x = ((unsigned)bfbits(b) << 16) | (unsigned)bfbits(a);
    r.y = ((unsigned)bfbits(d) << 16) | (unsigned)bfbits(c);
    return r;
}

// ---------------- Router + top-8 + softmax + x->bf16 [R11-verified] ----------------
__global__ __launch_bounds__(256) void router_topk_kernel(
    const float* __restrict__ x, const float* __restrict__ wr,
    int* __restrict__ topk_idx, float* __restrict__ gates,
    __hip_bfloat16* __restrict__ xbf) {
    const int b4 = blockIdx.x * 4;
    const int tid = threadIdx.x;
    const int lane = tid & 63, w = tid >> 6;
    __shared__ float sx[4 * HIDDEN];       // 32 KB
    __shared__ float wrs[64 * NEXP];       // 16 KB

    const float* xb = x + (size_t)b4 * HIDDEN;
    __hip_bfloat16* xbb = xbf + (size_t)b4 * HIDDEN;
#pragma unroll
    for (int i = 0; i < 8; ++i) {
        int s = i * 256 + tid;
        float4 v = *(const float4*)(xb + s * 4);
        *(float4*)&sx[s * 4] = v;
        ((uint2*)xbb)[s] = pack4(v.x, v.y, v.z, v.w);
    }
    __syncthreads();

    float a0 = 0.f, a1 = 0.f, a2 = 0.f, a3 = 0.f;
    for (int c = 0; c < HIDDEN / 64; ++c) {
#pragma unroll
        for (int j = 0; j < 4; ++j)
            *(float4*)&wrs[tid * 16 + j * 4] =
                *(const float4*)(wr + c * 64 * NEXP + tid * 16 + j * 4);
        __syncthreads();
        const float* sxw = &sx[w * HIDDEN + c * 64];
#pragma unroll
        for (int dd = 0; dd < 64; dd += 4) {
            a0 = fmaf(sxw[dd + 0], wrs[(dd + 0) * NEXP + lane], a0);
            a1 = fmaf(sxw[dd + 1], wrs[(dd + 1) * NEXP + lane], a1);
            a2 = fmaf(sxw[dd + 2], wrs[(dd + 2) * NEXP + lane], a2);
            a3 = fmaf(sxw[dd + 3], wrs[(dd + 3) * NEXP + lane], a3);
        }
        __syncthreads();
    }
    float cur = (a0 + a1) + (a2 + a3);

    const int t = b4 + w;
    float topv[TOPK];
    int topi[TOPK];
#pragma unroll
    for (int k = 0; k < TOPK; ++k) {
        float bv = cur;
        int bi = lane;
#pragma unroll
        for (int off = 32; off > 0; off >>= 1) {
            float ov = __shfl_xor(bv, off, 64);
            int oi = __shfl_xor(bi, off, 64);
            if (ov > bv || (ov == bv && oi < bi)) { bv = ov; bi = oi; }
        }
        topv[k] = bv;
        topi[k] = bi;
        if (lane == bi) cur = -INFINITY;
    }
    if (lane == 0) {
        float m = topv[0];
        float ex[TOPK], s = 0.f;
#pragma unroll
        for (int k = 0; k < TOPK; ++k) { ex[k] = __expf(topv[k] - m); s += ex[k]; }
        float inv = 1.f / s;
#pragma unroll
        for (int k = 0; k < TOPK; ++k) {
            gates[t * TOPK + k] = ex[k] * inv;
            topk_idx[t * TOPK + k] = topi[k];
        }
    }
}

// ---------------- Deterministic bucket build ----------------
__global__ void build_buckets_kernel(const int* __restrict__ topk_idx,
                                     const float* __restrict__ gates,
                                     int* __restrict__ bucket_tok,
                                     float* __restrict__ bucket_gate,
                                     int* __restrict__ count) {
    const int e = blockIdx.x;
    const int tid = threadIdx.x;
    __shared__ int scan[256];
    const int t0 = tid * 2;
    int f0 = 0, f1 = 0;
    float g0 = 0.f, g1 = 0.f;
#pragma unroll
    for (int k = 0; k < TOPK; ++k) {
        if (topk_idx[t0 * TOPK + k] == e) { f0 = 1; g0 = gates[t0 * TOPK + k]; }
        if (topk_idx[(t0 + 1) * TOPK + k] == e) { f1 = 1; g1 = gates[(t0 + 1) * TOPK + k]; }
    }
    int s = f0 + f1;
    scan[tid] = s;
    __syncthreads();
    for (int off = 1; off < 256; off <<= 1) {
        int add = (tid >= off) ? scan[tid - off] : 0;
        __syncthreads();
        scan[tid] += add;
        __syncthreads();
    }
    int excl = scan[tid] - s;
    if (f0) { bucket_tok[e * NTOK + excl] = t0; bucket_gate[e * NTOK + excl] = g0; }
    if (f1) { bucket_tok[e * NTOK + excl + f0] = t0 + 1; bucket_gate[e * NTOK + excl + f0] = g1; }
    if (tid == 255) count[e] = scan[255];
}

// ---------------- gateup (R12 + W-tile XOR swizzle) ----------------
// Only change vs R12: W-tile LDS column swizzled col' = col ^ (((row>>2)&3)<<4)
// on BOTH write and read. Breaks the 320B-lane-stride ds_write_b128 8-bank
// pattern (R11 PMC: 1.94e7 conflict cycles) -> 4-lane groups spread over 16
// banks. Logical tile content, global loads, fragments, math: identical.
__global__ __launch_bounds__(256, 2) void gateup_mfma(
    const __hip_bfloat16* __restrict__ xbf, const float* __restrict__ wg,
    const float* __restrict__ wu, const int* __restrict__ bucket_tok,
    const float* __restrict__ bucket_gate, const int* __restrict__ count,
    __hip_bfloat16* __restrict__ Aws) {
    const int e = blockIdx.x & 63;
    const int c0 = (blockIdx.x >> 6) * 128;
    __shared__ char smem[2 * BUFB] __attribute__((aligned(16)));
    __shared__ int base_sm;

    const int tid = threadIdx.x;
    const int n = count[e];
    if (tid < 64) {                    // base[e] via shfl scan
        int cv = count[tid];
        int inc = cv;
#pragma unroll
        for (int off = 1; off < 64; off <<= 1) {
            int v = __shfl_up(inc, off, 64);
            if (tid >= off) inc += v;
        }
        if (tid == e) base_sm = inc - cv;
    }
    __syncthreads();
    const int b0 = base_sm;
    if (n == 0) return;

    const int lane = tid & 63, w = tid >> 6;
    const int q = lane >> 4, r16 = lane & 15;

    const int m_ = tid >> 7;           // 0 gate, 1 up
    const int s_ = tid & 127;
    const int c4 = (s_ & 31) * 4;      // col group (row base in LDS)
    const int kb = (s_ >> 5) * 8;      // k base (0,8,16,24)
    const float* wsrc = ((m_ == 0) ? wg : wu) + (size_t)e * HIDDEN * INTER
                        + (size_t)kb * INTER + c0 + c4;
    // write swizzle: (row>>2)&3 == tid&3 for all 4 rows of this thread
    const unsigned wldso = (unsigned)((m_ * 128 + c4) * ROWB
                                      + ((kb * 2) ^ ((tid & 3) << 4)));
    // read swizzle: rows sub*16+r16 -> (row>>2)&3 == (r16>>2)&3
    const unsigned colswz = (unsigned)((q * 16) ^ (((r16 >> 2) & 3) << 4));

    const int xr0 = tid >> 2, xc0 = tid & 3;
    const int slot1 = 256 + tid;
    const int xr1 = slot1 >> 2, xc1 = slot1 & 3;
    const bool x1v = tid < 128;
    const unsigned xldso0 = (unsigned)(XOFF + xr0 * ROWB + xc0 * 16);
    const unsigned xldso1 = (unsigned)(XOFF + xr1 * ROWB + xc1 * 16);

    for (int m0 = 0; m0 < n; m0 += MT) {
        int p0 = m0 + xr0;
        int tk0 = (p0 < n) ? bucket_tok[e * NTOK + p0] : 0;
        const __hip_bfloat16* xp0 = xbf + (size_t)tk0 * HIDDEN + xc0 * 8;
        int p1 = m0 + xr1;
        int tk1 = (x1v && p1 < n) ? bucket_tok[e * NTOK + p1] : 0;
        const __hip_bfloat16* xp1 = xbf + (size_t)tk1 * HIDDEN + xc1 * 8;

        floatx4 acc[6][4];
#pragma unroll
        for (int ms = 0; ms < 6; ++ms)
#pragma unroll
            for (int s = 0; s < 4; ++s) acc[ms][s] = (floatx4){0.f, 0.f, 0.f, 0.f};

        float4 wA[8], wB[8];
        uint4 xA0, xA1, xB0, xB1;

        auto issueA = [&](int kt) {
            const float* p = wsrc + (size_t)kt * 32 * INTER;
#pragma unroll
            for (int j = 0; j < 8; ++j) wA[j] = *(const float4*)(p + (size_t)j * INTER);
            xA0 = *(const uint4*)(xp0 + kt * 32);
            if (x1v) xA1 = *(const uint4*)(xp1 + kt * 32);
        };
        auto issueB = [&](int kt) {
            const float* p = wsrc + (size_t)kt * 32 * INTER;
#pragma unroll
            for (int j = 0; j < 8; ++j) wB[j] = *(const float4*)(p + (size_t)j * INTER);
            xB0 = *(const uint4*)(xp0 + kt * 32);
            if (x1v) xB1 = *(const uint4*)(xp1 + kt * 32);
        };
        auto writeLDS = [&](char* buf, float4 (&wv)[8], uint4& x0, uint4& x1) {
#pragma unroll
            for (int i = 0; i < 4; ++i) {
                uint2 lo = pack4(wv[0][i], wv[1][i], wv[2][i], wv[3][i]);
                uint2 hi = pack4(wv[4][i], wv[5][i], wv[6][i], wv[7][i]);
                uint4 v; v.x = lo.x; v.y = lo.y; v.z = hi.x; v.w = hi.y;
                *(uint4*)(buf + wldso + i * ROWB) = v;
            }
            *(uint4*)(buf + xldso0) = x0;
            if (x1v) *(uint4*)(buf + xldso1) = x1;
        };
        auto compute = [&](const char* buf) {
            shortx8 bfr[4];
#pragma unroll
            for (int s = 0; s < 2; ++s) {
                bfr[s]     = *(const shortx8*)(buf + ((2 * w + s) * 16 + r16) * ROWB + colswz);
                bfr[2 + s] = *(const shortx8*)(buf + ((128 + (2 * w + s) * 16) + r16) * ROWB + colswz);
            }
            shortx8 afr[6];
#pragma unroll
            for (int ms = 0; ms < 6; ++ms)
                afr[ms] = *(const shortx8*)(buf + XOFF + (ms * 16 + r16) * ROWB + q * 16);
#pragma unroll
            for (int ms = 0; ms < 6; ++ms)
#pragma unroll
                for (int s = 0; s < 4; ++s)
                    acc[ms][s] = __builtin_amdgcn_mfma_f32_16x16x32_bf16(afr[ms], bfr[s], acc[ms][s], 0, 0, 0);
        };

        issueA(0);
        issueB(1);
        const int KTN = HIDDEN / 32;
        for (int kt2 = 0; kt2 < KTN / 2; ++kt2) {
            const int kt = 2 * kt2;
            writeLDS(smem, wA, xA0, xA1);                 // waits vmcnt on bank A only
            asm volatile("s_waitcnt lgkmcnt(0)" ::: "memory");
            __builtin_amdgcn_s_barrier();
            if (kt + 2 < KTN) issueA(kt + 2);             // depth-2 prefetch
            compute(smem);
            __builtin_amdgcn_s_barrier();
            writeLDS(smem + BUFB, wB, xB0, xB1);
            asm volatile("s_waitcnt lgkmcnt(0)" ::: "memory");
            __builtin_amdgcn_s_barrier();
            if (kt + 3 < KTN) issueB(kt + 3);
            compute(smem + BUFB);
            __builtin_amdgcn_s_barrier();
        }

        // epilogue: A = silu(h) * u * gate, bf16  (C: col=lane&15, row=4q+reg)
#pragma unroll
        for (int ms = 0; ms < 6; ++ms) {
#pragma unroll
            for (int j = 0; j < 2; ++j) {
                floatx4 h4 = acc[ms][j], u4 = acc[ms][j + 2];
#pragma unroll
                for (int rr = 0; rr < 4; ++rr) {
                    int ml = ms * 16 + 4 * q + rr;
                    int p = m0 + ml;
                    if (p < n) {
                        float gt = bucket_gate[e * NTOK + p];
                        float hv = h4[rr];
                        float av = hv / (1.f + __expf(-hv)) * u4[rr] * gt;
                        int col = c0 + (2 * w + j) * 16 + r16;
                        Aws[(size_t)(b0 + p) * INTER + col] = __float2bfloat16(av);
                    }
                }
            }
        }
    }
}

// ---------------- down (R12 + W-tile XOR swizzle) + scatter-add ----------------
__global__ __launch_bounds__(256, 2) void down_mfma(
    const __hip_bfloat16* __restrict__ Aws, const float* __restrict__ wd,
    const int* __restrict__ bucket_tok, const int* __restrict__ count,
    float* __restrict__ out) {
    const int e = blockIdx.x & 63;
    const int c0 = (blockIdx.x >> 6) * 256;
    __shared__ char smem[2 * BUFB] __attribute__((aligned(16)));
    __shared__ int base_sm;

    const int tid = threadIdx.x;
    const int n = count[e];
    if (tid < 64) {
        int cv = count[tid];
        int inc = cv;
#pragma unroll
        for (int off = 1; off < 64; off <<= 1) {
            int v = __shfl_up(inc, off, 64);
            if (tid >= off) inc += v;
        }
        if (tid == e) base_sm = inc - cv;
    }
    __syncthreads();
    const int b0 = base_sm;
    if (n == 0) return;

    const int lane = tid & 63, w = tid >> 6;
    const int q = lane >> 4, r16 = lane & 15;

    const int c4 = (tid & 63) * 4;
    const int kb = (tid >> 6) * 8;
    const float* wsrc = wd + (size_t)e * INTER * HIDDEN + (size_t)kb * HIDDEN + c0 + c4;
    const unsigned wldso = (unsigned)(c4 * ROWB + ((kb * 2) ^ ((tid & 3) << 4)));
    const unsigned colswz = (unsigned)((q * 16) ^ (((r16 >> 2) & 3) << 4));

    const int xr0 = tid >> 2, xc0 = tid & 3;
    const int slot1 = 256 + tid;
    const int xr1 = slot1 >> 2, xc1 = slot1 & 3;
    const bool x1v = tid < 128;
    const unsigned xldso0 = (unsigned)(XOFF + xr0 * ROWB + xc0 * 16);
    const unsigned xldso1 = (unsigned)(XOFF + xr1 * ROWB + xc1 * 16);

    for (int m0 = 0; m0 < n; m0 += MT) {
        const __hip_bfloat16* ap0 = Aws + (size_t)(b0 + m0 + xr0) * INTER + xc0 * 8;
        const __hip_bfloat16* ap1 = Aws + (size_t)(b0 + m0 + xr1) * INTER + xc1 * 8;

        floatx4 acc[6][4];
#pragma unroll
        for (int ms = 0; ms < 6; ++ms)
#pragma unroll
            for (int s = 0; s < 4; ++s) acc[ms][s] = (floatx4){0.f, 0.f, 0.f, 0.f};

        float4 wA[8], wB[8];
        uint4 aA0, aA1, aB0, aB1;

        auto issueA = [&](int kt) {
            const float* p = wsrc + (size_t)kt * 32 * HIDDEN;
#pragma unroll
            for (int j = 0; j < 8; ++j) wA[j] = *(const float4*)(p + (size_t)j * HIDDEN);
            aA0 = *(const uint4*)(ap0 + kt * 32);
            if (x1v) aA1 = *(const uint4*)(ap1 + kt * 32);
        };
        auto issueB = [&](int kt) {
            const float* p = wsrc + (size_t)kt * 32 * HIDDEN;
#pragma unroll
            for (int j = 0; j < 8; ++j) wB[j] = *(const float4*)(p + (size_t)j * HIDDEN);
            aB0 = *(const uint4*)(ap0 + kt * 32);
            if (x1v) aB1 = *(const uint4*)(ap1 + kt * 32);
        };
        auto writeLDS = [&](char* buf, float4 (&wv)[8], uint4& a0, uint4& a1) {
#pragma unroll
            for (int i = 0; i < 4; ++i) {
                uint2 lo = pack4(wv[0][i], wv[1][i], wv[2][i], wv[3][i]);
                uint2 hi = pack4(wv[4][i], wv[5][i], wv[6][i], wv[7][i]);
                uint4 v; v.x = lo.x; v.y = lo.y; v.z = hi.x; v.w = hi.y;
                *(uint4*)(buf + wldso + i * ROWB) = v;
            }
            *(uint4*)(buf + xldso0) = a0;
            if (x1v) *(uint4*)(buf + xldso1) = a1;
        };
        auto compute = [&](const char* buf) {
            shortx8 bfr[4];
#pragma unroll
            for (int s = 0; s < 4; ++s)
                bfr[s] = *(const shortx8*)(buf + ((4 * w + s) * 16 + r16) * ROWB + colswz);
            shortx8 afr[6];
#pragma unroll
            for (int ms = 0; ms < 6; ++ms)
                afr[ms] = *(const shortx8*)(buf + XOFF + (ms * 16 + r16) * ROWB + q * 16);
#pragma unroll
            for (int ms = 0; ms < 6; ++ms)
#pragma unroll
                for (int s = 0; s < 4; ++s)
                    acc[ms][s] = __builtin_amdgcn_mfma_f32_16x16x32_bf16(afr[ms], bfr[s], acc[ms][s], 0, 0, 0);
        };

        issueA(0);
        issueB(1);
        const int KTN = INTER / 32;
        for (int kt2 = 0; kt2 < KTN / 2; ++kt2) {
            const int kt = 2 * kt2;
            writeLDS(smem, wA, aA0, aA1);
            asm volatile("s_waitcnt lgkmcnt(0)" ::: "memory");
            __builtin_amdgcn_s_barrier();
            if (kt + 2 < KTN) issueA(kt + 2);
            compute(smem);
            __builtin_amdgcn_s_barrier();
            writeLDS(smem + BUFB, wB, aB0, aB1);
            asm volatile("s_waitcnt lgkmcnt(0)" ::: "memory");
            __builtin_amdgcn_s_barrier();
            if (kt + 3 < KTN) issueB(kt + 3);
            compute(smem + BUFB);
            __builtin_amdgcn_s_barrier();
        }

#pragma unroll
        for (int ms = 0; ms < 6; ++ms) {
#pragma unroll
            for (int rr = 0; rr < 4; ++rr) {
                int ml = ms * 16 + 4 * q + rr;
                int p = m0 + ml;
                if (p < n) {
                    int tok = bucket_tok[e * NTOK + p];
                    float* orow = out + (size_t)tok * HIDDEN;
#pragma unroll
                    for (int s = 0; s < 4; ++s) {
                        int col = c0 + (4 * w + s) * 16 + r16;
                        unsafeAtomicAdd(&orow[col], acc[ms][s][rr]);
                    }
                }
            }
        }
    }
}

extern "C" void kernel_launch(void* const* d_in, const int* in_sizes, int n_in,
                              void* d_out, int out_size, void* d_ws, size_t ws_size,
                              hipStream_t stream) {
    const float* x = (const float*)d_in[0];
    const float* wr = (const float*)d_in[1];
    const float* wg = (const float*)d_in[2];
    const float* wu = (const float*)d_in[3];
    const float* wd = (const float*)d_in[4];
    float* out = (float*)d_out;

    char* ws = (char*)d_ws;
    size_t off = 0;
    auto alloc = [&](size_t bytes) {
        void* p = ws + off;
        off = (off + bytes + 255) & ~(size_t)255;
        return p;
    };
    int* topk_idx = (int*)alloc(NTOK * TOPK * sizeof(int));
    float* gates = (float*)alloc(NTOK * TOPK * sizeof(float));
    int* bucket_tok = (int*)alloc(NEXP * NTOK * sizeof(int));
    float* bucket_gate = (float*)alloc(NEXP * NTOK * sizeof(float));
    int* count = (int*)alloc(NEXP * sizeof(int));
    __hip_bfloat16* Aws = (__hip_bfloat16*)alloc((size_t)AWS_ROWS * INTER * sizeof(__hip_bfloat16));
    __hip_bfloat16* xbf = (__hip_bfloat16*)alloc((size_t)NTOK * HIDDEN * sizeof(__hip_bfloat16));
    (void)ws_size;

    hipMemsetAsync(d_out, 0, (size_t)NTOK * HIDDEN * sizeof(float), stream);

    router_topk_kernel<<<NTOK / 4, 256, 0, stream>>>(x, wr, topk_idx, gates, xbf);
    build_buckets_kernel<<<NEXP, 256, 0, stream>>>(topk_idx, gates, bucket_tok, bucket_gate, count);
    gateup_mfma<<<NEXP * 8, 256, 0, stream>>>(xbf, wg, wu, bucket_tok, bucket_gate, count, Aws);
    down_mfma<<<NEXP * 8, 256, 0, stream>>>(Aws, wd, bucket_tok, count, out);
}